// Round 9
// baseline (812.788 us; speedup 1.0000x reference)
//
#include <hip/hip_runtime.h>
#include <hip/hip_bf16.h>
#include <math.h>

#define N_NODES 3072
#define N_EDGES 30720
#define G_GRAPHS 16
#define IN_DIM 32
#define EMB 300
#define T_TOWERS 6
#define F_OUT 50
#define N_INNER 4
#define EPS_V 1e-5f
#define POOL_S 8
#define KC_PREP 10

typedef unsigned short u16;
typedef __attribute__((ext_vector_type(8))) unsigned short u16x8;
typedef __attribute__((ext_vector_type(4))) unsigned short u16x4;
typedef __attribute__((ext_vector_type(8))) short bf16x8;
typedef __attribute__((ext_vector_type(4))) float f32x4;

__device__ inline u16 f2bf(float v) {
    union { float f; unsigned u; } x; x.f = v;
    unsigned r = x.u + 0x7FFF + ((x.u >> 16) & 1);
    return (u16)(r >> 16);
}
__device__ inline float bf2f(u16 h) {
    union { unsigned u; float f; } x; x.u = ((unsigned)h) << 16;
    return x.f;
}
__device__ inline void split2(float v, u16* ph, u16* pl) {
    u16 h = f2bf(v);
    *ph = h;
    *pl = f2bf(v - bf2f(h));
}

// ---------------- setup kernels ----------------

__global__ void zero_int_k(int* p, int n) {
    int i = blockIdx.x * blockDim.x + threadIdx.x;
    if (i < n) p[i] = 0;
}

__global__ void count_deg_k(const int* __restrict__ dst, int* __restrict__ deg, int e_cnt) {
    int e = blockIdx.x * blockDim.x + threadIdx.x;
    if (e < e_cnt) atomicAdd(&deg[dst[e]], 1);
}

__global__ void scan_off_k(const int* __restrict__ deg, int* __restrict__ off) {
    __shared__ int sums[1024];
    int tid = threadIdx.x;
    int base = tid * 3;
    int v0 = deg[base], v1 = deg[base + 1], v2 = deg[base + 2];
    int s = v0 + v1 + v2;
    sums[tid] = s;
    __syncthreads();
    for (int d = 1; d < 1024; d <<= 1) {
        int x = (tid >= d) ? sums[tid - d] : 0;
        __syncthreads();
        sums[tid] += x;
        __syncthreads();
    }
    int excl = sums[tid] - s;
    off[base] = excl;
    off[base + 1] = excl + v0;
    off[base + 2] = excl + v0 + v1;
    if (tid == 1023) off[N_NODES] = sums[1023];
}

__global__ void init_cur_k(const int* __restrict__ off, int* __restrict__ cur, int n) {
    int i = blockIdx.x * blockDim.x + threadIdx.x;
    if (i < n) cur[i] = off[i];
}

__global__ void scatter_k(const int* __restrict__ dst, int* __restrict__ cur,
                          int* __restrict__ ce, int e_cnt) {
    int e = blockIdx.x * blockDim.x + threadIdx.x;
    if (e < e_cnt) {
        int p = atomicAdd(&cur[dst[e]], 1);
        ce[p] = e;
    }
}

__global__ void gather_idx_k(const int* __restrict__ ce, const int* __restrict__ srcI,
                             const float* __restrict__ ea,
                             int* __restrict__ gs, float2* __restrict__ eag, int e_cnt) {
    int p = blockIdx.x * blockDim.x + threadIdx.x;
    if (p < e_cnt) {
        int e = ce[p];
        gs[p] = srcI[e];
        eag[p] = make_float2(ea[2 * e], ea[2 * e + 1]);
    }
}

__global__ void avg_log_k(const float* __restrict__ hist, float* __restrict__ out) {
    __shared__ float a[64], b[64];
    int i = threadIdx.x;
    float l = logf((float)i + 1.0f);
    a[i] = l * hist[i];
    b[i] = hist[i];
    __syncthreads();
    if (i == 0) {
        float sa = 0.f, sb = 0.f;
        for (int j = 0; j < 64; j++) { sa += a[j]; sb += b[j]; }
        out[0] = sa / sb;
    }
}

__global__ void node_scalers_k(const int* __restrict__ deg, const float* __restrict__ avg,
                               float* __restrict__ degc, float* __restrict__ amp,
                               float* __restrict__ att, int n) {
    int i = blockIdx.x * blockDim.x + threadIdx.x;
    if (i < n) {
        float d = fmaxf((float)deg[i], 1.0f);
        degc[i] = d;
        float lg = logf(d + 1.0f);
        float al = avg[0];
        amp[i] = lg / al;
        att[i] = al / lg;
    }
}

// ---------------- per-layer edge-weight prep ----------------
__global__ void zero3_k(float* __restrict__ W3eff, float* __restrict__ cb, int TF) {
    int i = blockIdx.x * blockDim.x + threadIdx.x;
    if (i < 2 * TF) W3eff[i] = 0.f;
    else if (i < 3 * TF) cb[i - 2 * TF] = 0.f;
}

__global__ void prep_edge2_k(const float* __restrict__ ew, const float* __restrict__ eb,
                             const float* __restrict__ prew, const float* __restrict__ preb,
                             float* __restrict__ W3eff, float* __restrict__ cb,
                             int Fh, int TF) {
    int tf = blockIdx.x * 256 + threadIdx.x;
    if (tf >= TF) return;
    int j = blockIdx.y, kc = blockIdx.z;
    int chunk = (Fh + KC_PREP - 1) / KC_PREP;
    int k0 = kc * chunk, k1 = min(k0 + chunk, Fh);
    if (k0 >= Fh) return;
    int t = tf / Fh, f = tf - t * Fh;
    const float* col = prew + ((size_t)t * 3 * Fh + 2 * Fh) * Fh + f;
    const float* vec = (j < 2) ? (ew + (size_t)j * Fh) : eb;
    float s = 0.f;
    for (int k = k0; k < k1; k++) s += vec[k] * col[(size_t)k * Fh];
    if (j < 2) atomicAdd(&W3eff[(size_t)j * TF + tf], s);
    else {
        if (kc == 0) s += preb[(size_t)t * Fh + f];
        atomicAdd(&cb[tf], s);
    }
}

// ---------------- generic LDS-tiled transpose + split (dl optional) ----------------
__global__ void cvt_tr_k(const float* __restrict__ src, u16* __restrict__ dh, u16* __restrict__ dl,
                         int F2, int F3,
                         long long s1, long long s2, long long s3, long long soff,
                         long long d1, long long d2, long long d3,
                         int R, int C, int sRow, int dRow) {
    __shared__ float tile[64][65];
    int z = blockIdx.z;
    int c3 = z % F3; int zz = z / F3; int c2 = zz % F2; int c1 = zz / F2;
    src += c1 * s1 + c2 * s2 + c3 * s3 + soff;
    long long doff = c1 * d1 + c2 * d2 + c3 * d3;
    dh += doff; if (dl) dl += doff;
    int r0 = blockIdx.x * 64, c0 = blockIdx.y * 64;
    int tx = threadIdx.x & 63, ty = threadIdx.x >> 6;
#pragma unroll
    for (int i = 0; i < 64; i += 4) {
        int r = r0 + ty + i, c = c0 + tx;
        tile[ty + i][tx] = (r < R && c < C) ? src[(size_t)r * sRow + c] : 0.f;
    }
    __syncthreads();
#pragma unroll
    for (int i = 0; i < 64; i += 4) {
        int c = c0 + ty + i, r = r0 + tx;
        if (c < C && r < dRow) {
            float v = tile[tx][ty + i];
            u16 h = f2bf(v);
            dh[(size_t)c * dRow + r] = h;
            if (dl) dl[(size_t)c * dRow + r] = f2bf(v - bf2f(h));
        }
    }
}

// ---------------- layer-0 (tiny) conversions ----------------
__global__ void cvt_wu0_k(const float* __restrict__ prew0, u16* __restrict__ Wh, u16* __restrict__ Wl) {
    int p = blockIdx.z;
    int idx = blockIdx.x * 256 + threadIdx.x;
    if (idx >= 192 * 32) return;
    int n = idx / 32, k = idx - n * 32;
    int t = n / 32, f = n - t * 32;
    float v = prew0[((size_t)t * 96 + p * 32 + k) * 32 + f];
    size_t o = (size_t)p * 192 * 32 + idx;
    split2(v, &Wh[o], &Wl[o]);
}

__global__ void cvt_wh0_k(const float* __restrict__ postw0, u16* __restrict__ Wh, u16* __restrict__ Wl) {
    int idx = blockIdx.x * 256 + threadIdx.x;
    if (idx >= 320 * 32) return;
    int n = idx / 32, k = idx - n * 32;
    float v = 0.f;
    if (n < 300) {
        int t = n / 50, j = n - t * 50;
        v = postw0[((size_t)t * 416 + k) * 50 + j];
    }
    split2(v, &Wh[idx], &Wl[idx]);
}

__global__ void cvt_wp0_k(const float* __restrict__ postw0, u16* __restrict__ Wh) {
    int t = blockIdx.z;
    int idx = blockIdx.x * 256 + threadIdx.x;
    if (idx >= 192 * 128) return;
    int gn = idx / 128, k = idx - gn * 128;
    if (gn >= 150) return;
    int s = gn / 50, j = gn - s * 50;
    float v = postw0[((size_t)t * 416 + 32 + s * 128 + k) * 50 + j];
    Wh[(size_t)t * 192 * 128 + idx] = f2bf(v);
}

__global__ void cvt_x_k(const float* __restrict__ x, u16* __restrict__ Xh, u16* __restrict__ Xl) {
    int idx = blockIdx.x * 256 + threadIdx.x;
    if (idx >= 3072 * 32) return;
    split2(x[idx], &Xh[idx], &Xl[idx]);
}

// swizzled LDS slot: 16B-slot s at row r lives at physical slot s ^ ((r>>1)&3)
#define SWZ(row, s) (((s) ^ (((row) >> 1) & 3)) << 3)

// ---------------- fused U1+U2+H GEMM (A,B hi/lo split, 3-MFMA, prefetch, swizzle) ----
__global__ __launch_bounds__(256)
void mfma_fu_k(const u16* __restrict__ Ah, const u16* __restrict__ Al, int lda,
               const u16* __restrict__ Bh, const u16* __restrict__ Bl, int ldb,
               int K, const float* __restrict__ cb,
               float* __restrict__ U1, int ldu1,
               u16* __restrict__ U2, int ldu2,
               float* __restrict__ Hout, int ldh,
               int us1, int us2, int N1, int NH) {
    __shared__ u16 As_h[128][32], As_l[128][32], Bs_h[64][32], Bs_l[64][32];
    const int tid = threadIdx.x;
    const int wave = tid >> 6, lane = tid & 63;
    const int wr = wave >> 1, wc = wave & 1;
    const int fr = lane & 15, fkb = lane >> 4;
    const int m0 = blockIdx.x * 128, n0 = blockIdx.y * 64;
    const int srow = tid >> 2, sc = tid & 3, sk = sc * 8;
    const int wsk = SWZ(srow, sc);
    const u16* pa0h = Ah + (size_t)(m0 + srow) * lda + sk;
    const u16* pa1h = Ah + (size_t)(m0 + 64 + srow) * lda + sk;
    const u16* pa0l = Al + (size_t)(m0 + srow) * lda + sk;
    const u16* pa1l = Al + (size_t)(m0 + 64 + srow) * lda + sk;
    const u16* pb0h = Bh + (size_t)(n0 + srow) * ldb + sk;
    const u16* pb0l = Bl + (size_t)(n0 + srow) * ldb + sk;
    u16x8 a0h = *(const u16x8*)pa0h;
    u16x8 a1h = *(const u16x8*)pa1h;
    u16x8 a0l = *(const u16x8*)pa0l;
    u16x8 a1l = *(const u16x8*)pa1l;
    u16x8 b0h = *(const u16x8*)pb0h;
    u16x8 b0l = *(const u16x8*)pb0l;

    f32x4 acc[4][2];
#pragma unroll
    for (int i = 0; i < 4; i++)
#pragma unroll
        for (int j = 0; j < 2; j++) acc[i][j] = (f32x4){0.f, 0.f, 0.f, 0.f};

    for (int k0 = 0; k0 < K; k0 += 32) {
        __syncthreads();
        *(u16x8*)&As_h[srow][wsk] = a0h;
        *(u16x8*)&As_h[64 + srow][wsk] = a1h;
        *(u16x8*)&As_l[srow][wsk] = a0l;
        *(u16x8*)&As_l[64 + srow][wsk] = a1l;
        *(u16x8*)&Bs_h[srow][wsk] = b0h;
        *(u16x8*)&Bs_l[srow][wsk] = b0l;
        __syncthreads();
        int kn = k0 + 32;
        if (kn < K) {
            a0h = *(const u16x8*)(pa0h + kn);
            a1h = *(const u16x8*)(pa1h + kn);
            a0l = *(const u16x8*)(pa0l + kn);
            a1l = *(const u16x8*)(pa1l + kn);
            b0h = *(const u16x8*)(pb0h + kn);
            b0l = *(const u16x8*)(pb0l + kn);
        }
        bf16x8 ah[4], al[4], bh[2], bl[2];
#pragma unroll
        for (int i = 0; i < 4; i++) {
            int ar = wr * 64 + i * 16 + fr;
            ah[i] = *(const bf16x8*)&As_h[ar][SWZ(ar, fkb)];
            al[i] = *(const bf16x8*)&As_l[ar][SWZ(ar, fkb)];
        }
#pragma unroll
        for (int j = 0; j < 2; j++) {
            int br = wc * 32 + j * 16 + fr;
            bh[j] = *(const bf16x8*)&Bs_h[br][SWZ(br, fkb)];
            bl[j] = *(const bf16x8*)&Bs_l[br][SWZ(br, fkb)];
        }
#pragma unroll
        for (int i = 0; i < 4; i++)
#pragma unroll
            for (int j = 0; j < 2; j++) {
                acc[i][j] = __builtin_amdgcn_mfma_f32_16x16x32_bf16(ah[i], bh[j], acc[i][j], 0, 0, 0);
                acc[i][j] = __builtin_amdgcn_mfma_f32_16x16x32_bf16(ah[i], bl[j], acc[i][j], 0, 0, 0);
                acc[i][j] = __builtin_amdgcn_mfma_f32_16x16x32_bf16(al[i], bh[j], acc[i][j], 0, 0, 0);
            }
    }
#pragma unroll
    for (int i = 0; i < 4; i++)
#pragma unroll
        for (int j = 0; j < 2; j++) {
            int col = n0 + wc * 32 + j * 16 + fr;
            int rowb = m0 + wr * 64 + i * 16 + fkb * 4;
            if (col < us1) {
                if (col < N1) {
                    float bv = cb[col];
#pragma unroll
                    for (int r = 0; r < 4; r++)
                        U1[(size_t)(rowb + r) * ldu1 + col] = acc[i][j][r] + bv;
                }
            } else if (col < us2) {
                int ec = col - us1;
                if (ec < N1) {
#pragma unroll
                    for (int r = 0; r < 4; r++)
                        U2[(size_t)(rowb + r) * ldu2 + ec] = f2bf(acc[i][j][r]);
                }
            } else {
                int ec = col - us2;
                if (ec < NH) {
#pragma unroll
                    for (int r = 0; r < 4; r++)
                        Hout[(size_t)(rowb + r) * ldh + ec] = acc[i][j][r];
                }
            }
        }
}

// ---------------- generic MFMA GEMM (templated splits + tile M, prefetch, swizzle) ----
template<int ASINGLE, int BSINGLE, int TM>
__global__ __launch_bounds__(256)
void mfma_gemm_t(const u16* __restrict__ Ah, const u16* __restrict__ Al, int lda, int aZstr,
                 const u16* __restrict__ Bh, const u16* __restrict__ Bl, int ldb, int bZstr,
                 int K, const float* __restrict__ bias,
                 float* __restrict__ C, int ldc, int cZstr, int Nout, int relu,
                 u16* __restrict__ C2h, u16* __restrict__ C2l, int ldc2, int c2Zstr) {
    constexpr int MI = TM / 32;
    constexpr int AR = TM / 64;
    __shared__ u16 As_h[TM][32];
    __shared__ u16 As_l[ASINGLE ? 1 : TM][32];
    __shared__ u16 Bs_h[64][32];
    __shared__ u16 Bs_l[BSINGLE ? 1 : 64][32];
    const int z = blockIdx.z;
    Ah += (size_t)z * aZstr;
    if (!ASINGLE) Al += (size_t)z * aZstr;
    Bh += (size_t)z * bZstr;
    if (!BSINGLE) Bl += (size_t)z * bZstr;
    if (C) C += (size_t)z * cZstr;
    if (C2h) C2h += (size_t)z * c2Zstr;
    if (C2l) C2l += (size_t)z * c2Zstr;
    const int tid = threadIdx.x;
    const int wave = tid >> 6, lane = tid & 63;
    const int wr = wave >> 1, wc = wave & 1;
    const int fr = lane & 15, fkb = lane >> 4;
    const int m0 = blockIdx.x * TM, n0 = blockIdx.y * 64;
    const int srow = tid >> 2, sc = tid & 3, sk = sc * 8;
    const int wsk = SWZ(srow, sc);

    u16x8 rah[AR], ral[ASINGLE ? 1 : AR], rbh, rbl;
#pragma unroll
    for (int ii = 0; ii < AR; ii++) {
        rah[ii] = *(const u16x8*)(Ah + (size_t)(m0 + ii * 64 + srow) * lda + sk);
        if (!ASINGLE) ral[ii] = *(const u16x8*)(Al + (size_t)(m0 + ii * 64 + srow) * lda + sk);
    }
    rbh = *(const u16x8*)(Bh + (size_t)(n0 + srow) * ldb + sk);
    if (!BSINGLE) rbl = *(const u16x8*)(Bl + (size_t)(n0 + srow) * ldb + sk);

    f32x4 acc[MI][2];
#pragma unroll
    for (int i = 0; i < MI; i++)
#pragma unroll
        for (int j = 0; j < 2; j++) acc[i][j] = (f32x4){0.f, 0.f, 0.f, 0.f};

    for (int k0 = 0; k0 < K; k0 += 32) {
        __syncthreads();
#pragma unroll
        for (int ii = 0; ii < AR; ii++) {
            *(u16x8*)&As_h[ii * 64 + srow][wsk] = rah[ii];
            if (!ASINGLE) *(u16x8*)&As_l[ii * 64 + srow][wsk] = ral[ii];
        }
        *(u16x8*)&Bs_h[srow][wsk] = rbh;
        if (!BSINGLE) *(u16x8*)&Bs_l[srow][wsk] = rbl;
        __syncthreads();
        int kn = k0 + 32;
        if (kn < K) {
#pragma unroll
            for (int ii = 0; ii < AR; ii++) {
                rah[ii] = *(const u16x8*)(Ah + (size_t)(m0 + ii * 64 + srow) * lda + kn + sk);
                if (!ASINGLE) ral[ii] = *(const u16x8*)(Al + (size_t)(m0 + ii * 64 + srow) * lda + kn + sk);
            }
            rbh = *(const u16x8*)(Bh + (size_t)(n0 + srow) * ldb + kn + sk);
            if (!BSINGLE) rbl = *(const u16x8*)(Bl + (size_t)(n0 + srow) * ldb + kn + sk);
        }
        bf16x8 ah[MI], al[MI], bh[2], bl[2];
#pragma unroll
        for (int i = 0; i < MI; i++) {
            int ar = wr * (TM / 2) + i * 16 + fr;
            ah[i] = *(const bf16x8*)&As_h[ar][SWZ(ar, fkb)];
            if (!ASINGLE) al[i] = *(const bf16x8*)&As_l[ar][SWZ(ar, fkb)];
        }
#pragma unroll
        for (int j = 0; j < 2; j++) {
            int br = wc * 32 + j * 16 + fr;
            bh[j] = *(const bf16x8*)&Bs_h[br][SWZ(br, fkb)];
            if (!BSINGLE) bl[j] = *(const bf16x8*)&Bs_l[br][SWZ(br, fkb)];
        }
#pragma unroll
        for (int i = 0; i < MI; i++)
#pragma unroll
            for (int j = 0; j < 2; j++) {
                acc[i][j] = __builtin_amdgcn_mfma_f32_16x16x32_bf16(ah[i], bh[j], acc[i][j], 0, 0, 0);
                if (!BSINGLE)
                    acc[i][j] = __builtin_amdgcn_mfma_f32_16x16x32_bf16(ah[i], bl[j], acc[i][j], 0, 0, 0);
                if (!ASINGLE)
                    acc[i][j] = __builtin_amdgcn_mfma_f32_16x16x32_bf16(al[i], bh[j], acc[i][j], 0, 0, 0);
            }
    }
#pragma unroll
    for (int i = 0; i < MI; i++)
#pragma unroll
        for (int j = 0; j < 2; j++) {
            int col = n0 + wc * 32 + j * 16 + fr;
            if (col < Nout) {
                float bv = bias ? bias[col] : 0.f;
                int rowb = m0 + wr * (TM / 2) + i * 16 + fkb * 4;
#pragma unroll
                for (int r = 0; r < 4; r++) {
                    float v = acc[i][j][r] + bv;
                    if (relu) v = fmaxf(v, 0.f);
                    if (C) C[(size_t)(rowb + r) * ldc + col] = v;
                    if (C2h) {
                        if (C2l) split2(v, &C2h[(size_t)(rowb + r) * ldc2 + col],
                                           &C2l[(size_t)(rowb + r) * ldc2 + col]);
                        else C2h[(size_t)(rowb + r) * ldc2 + col] = f2bf(v);
                    }
                }
            }
        }
}

// ---------------- aggregation (XCD feature-partitioned: block = 32 nodes x 8 q-lanes) ----
// physical bid -> xcd x = bid&7; feature-chunk qc = x + 8*(li/96) -> all node-chunks of
// a 64-feat slice land on one XCD -> per-XCD U2 working set ~1.5MB (L2-resident).
__global__ void agg_k(const float* __restrict__ U1, const u16* __restrict__ U2,
                      const float* __restrict__ W3eff,
                      const int* __restrict__ off, const int* __restrict__ gs,
                      const float2* __restrict__ eag, const float* __restrict__ degc,
                      u16* __restrict__ agg_h, int Fh, int TF, int u2ld, int QC) {
    int bid = blockIdx.x;
    int x = bid & 7, li = bid >> 3;
    int qq = li / 96, nc = li - qq * 96;
    int qc = x + 8 * qq;
    if (qc >= QC) return;
    int nt = TF >> 3;
    int ql = threadIdx.x & 7, nl = threadIdx.x >> 3;
    int q = qc * 8 + ql;
    if (q >= nt) return;
    int n = nc * 32 + nl;
    int tf = q << 3;
    float w0[8], w1[8], cc[8];
    *(float4*)&w0[0] = *(const float4*)(W3eff + tf);
    *(float4*)&w0[4] = *(const float4*)(W3eff + tf + 4);
    *(float4*)&w1[0] = *(const float4*)(W3eff + TF + tf);
    *(float4*)&w1[4] = *(const float4*)(W3eff + TF + tf + 4);
    *(float4*)&cc[0] = *(const float4*)(U1 + (size_t)n * TF + tf);
    *(float4*)&cc[4] = *(const float4*)(U1 + (size_t)n * TF + tf + 4);
    int beg = off[n], end = off[n + 1];
    float s1[8], s2[8], mn[8], mx[8];
#pragma unroll
    for (int r = 0; r < 8; r++) { s1[r] = 0.f; s2[r] = 0.f; mn[r] = INFINITY; mx[r] = -INFINITY; }
    int p = beg;
    for (; p + 1 < end; p += 2) {
        int sa = gs[p], sb = gs[p + 1];
        float2 ea0 = eag[p], ea1 = eag[p + 1];
        u16x8 ra = *(const u16x8*)(U2 + (size_t)sa * u2ld + tf);
        u16x8 rb = *(const u16x8*)(U2 + (size_t)sb * u2ld + tf);
#pragma unroll
        for (int r = 0; r < 8; r++) {
            float va = bf2f(ra[r]) + ea0.x * w0[r] + ea0.y * w1[r];
            s1[r] += va; s2[r] += va * va;
            mn[r] = fminf(mn[r], va); mx[r] = fmaxf(mx[r], va);
            float vb = bf2f(rb[r]) + ea1.x * w0[r] + ea1.y * w1[r];
            s1[r] += vb; s2[r] += vb * vb;
            mn[r] = fminf(mn[r], vb); mx[r] = fmaxf(mx[r], vb);
        }
    }
    if (p < end) {
        int sa = gs[p];
        float2 ea0 = eag[p];
        u16x8 ra = *(const u16x8*)(U2 + (size_t)sa * u2ld + tf);
#pragma unroll
        for (int r = 0; r < 8; r++) {
            float va = bf2f(ra[r]) + ea0.x * w0[r] + ea0.y * w1[r];
            s1[r] += va; s2[r] += va * va;
            mn[r] = fminf(mn[r], va); mx[r] = fmaxf(mx[r], va);
        }
    }
    float dc = degc[n];
    u16 o0[8], o1[8], o2[8], o3[8];
#pragma unroll
    for (int r = 0; r < 8; r++) {
        float mean = s1[r] / dc;
        float var = fmaxf(s2[r] / dc - mean * mean, 0.f);
        float sd = sqrtf(var + EPS_V);
        o0[r] = f2bf(mean + cc[r]);
        o1[r] = f2bf(mn[r] + cc[r]);
        o2[r] = f2bf(mx[r] + cc[r]);
        o3[r] = f2bf(sd);
    }
    int t0 = tf / Fh, f0 = tf - t0 * Fh;
    if (f0 + 8 <= Fh) {
        size_t base = ((size_t)n * 6 + t0) * 1216 + f0;
        *(u16x4*)(agg_h + base) = *(u16x4*)&o0[0];
        *(u16x4*)(agg_h + base + 4) = *(u16x4*)&o0[4];
        *(u16x4*)(agg_h + base + Fh) = *(u16x4*)&o1[0];
        *(u16x4*)(agg_h + base + Fh + 4) = *(u16x4*)&o1[4];
        *(u16x4*)(agg_h + base + 2 * Fh) = *(u16x4*)&o2[0];
        *(u16x4*)(agg_h + base + 2 * Fh + 4) = *(u16x4*)&o2[4];
        *(u16x4*)(agg_h + base + 3 * Fh) = *(u16x4*)&o3[0];
        *(u16x4*)(agg_h + base + 3 * Fh + 4) = *(u16x4*)&o3[4];
    } else {
#pragma unroll
        for (int r = 0; r < 8; r++) {
            int tfr = tf + r;
            int t = tfr / Fh, f = tfr - t * Fh;
            size_t base = ((size_t)n * 6 + t) * 1216 + f;
            agg_h[base] = o0[r];
            agg_h[base + Fh] = o1[r];
            agg_h[base + 2 * Fh] = o2[r];
            agg_h[base + 3 * Fh] = o3[r];
        }
    }
}

// ---------------- combine ----------------
__global__ void combine_k(const float* __restrict__ H, const float* __restrict__ P,
                          const float* __restrict__ amp, const float* __restrict__ att,
                          const float* __restrict__ postb,
                          u16* __restrict__ ph, u16* __restrict__ pl) {
    int idx = blockIdx.x * blockDim.x + threadIdx.x;
    if (idx >= N_NODES * EMB) return;
    int n = idx / EMB, tf = idx - n * EMB;
    int t = tf / F_OUT, j = tf - t * F_OUT;
    const float* Pr = P + (size_t)n * 900 + t * 150;
    float v = H[idx] + Pr[j] + amp[n] * Pr[F_OUT + j] + att[n] * Pr[2 * F_OUT + j]
            + postb[(size_t)t * F_OUT + j];
    split2(v, &ph[(size_t)n * 320 + tf], &pl[(size_t)n * 320 + tf]);
}

// ---------------- head ----------------

__global__ void pool_part_k(const float* __restrict__ h, float* __restrict__ part) {
    int idx = blockIdx.x * blockDim.x + threadIdx.x;
    if (idx >= POOL_S * G_GRAPHS * EMB) return;
    int s = idx / (G_GRAPHS * EMB), rem = idx - s * (G_GRAPHS * EMB);
    int g = rem / EMB, f = rem - g * EMB;
    const int per = N_NODES / G_GRAPHS;
    const int chunk = per / POOL_S;
    int r0 = g * per + s * chunk;
    float acc = 0.f;
#pragma unroll
    for (int i = 0; i < 24; i++) acc += h[(size_t)(r0 + i) * EMB + f];
    part[idx] = acc;
}

__global__ void pool_red_k(const float* __restrict__ part, float* __restrict__ gpool) {
    int idx = blockIdx.x * blockDim.x + threadIdx.x;
    if (idx >= G_GRAPHS * EMB) return;
    float s = 0.f;
#pragma unroll
    for (int i = 0; i < POOL_S; i++) s += part[(size_t)i * G_GRAPHS * EMB + idx];
    gpool[idx] = s;
}

__global__ void fc_wave_k(const float* __restrict__ A, const float* __restrict__ W,
                          const float* __restrict__ b, float* __restrict__ out,
                          int M, int K, int Nout, int relu) {
    int gw = (blockIdx.x * blockDim.x + threadIdx.x) >> 6;
    int lane = threadIdx.x & 63;
    if (gw >= M * Nout) return;
    int m = gw / Nout, j = gw - m * Nout;
    float s = 0.f;
    for (int k = lane; k < K; k += 64)
        s += A[(size_t)m * K + k] * W[(size_t)k * Nout + j];
#pragma unroll
    for (int o = 32; o > 0; o >>= 1) s += __shfl_xor(s, o);
    if (lane == 0) {
        float v = s + b[j];
        if (relu) v = fmaxf(v, 0.f);
        out[(size_t)m * Nout + j] = v;
    }
}

// ---------------- launcher ----------------

extern "C" void kernel_launch(void* const* d_in, const int* in_sizes, int n_in,
                              void* d_out, int out_size, void* d_ws, size_t ws_size,
                              hipStream_t stream) {
    const float* x        = (const float*)d_in[0];
    const float* eattr    = (const float*)d_in[1];
    const int*   eidx     = (const int*)d_in[2];
    const float* deg_hist = (const float*)d_in[4];
    const float* ew0      = (const float*)d_in[5];
    const float* eb0      = (const float*)d_in[6];
    const float* prew0    = (const float*)d_in[7];
    const float* preb0    = (const float*)d_in[8];
    const float* postw0   = (const float*)d_in[9];
    const float* postb0   = (const float*)d_in[10];
    const float* linw0    = (const float*)d_in[11];
    const float* linb0    = (const float*)d_in[12];
    const float* ew       = (const float*)d_in[13];
    const float* eb       = (const float*)d_in[14];
    const float* prew     = (const float*)d_in[15];
    const float* preb     = (const float*)d_in[16];
    const float* postw    = (const float*)d_in[17];
    const float* postb    = (const float*)d_in[18];
    const float* linw     = (const float*)d_in[19];
    const float* linb     = (const float*)d_in[20];
    const float* hw1      = (const float*)d_in[21];
    const float* hb1      = (const float*)d_in[22];
    const float* hw2      = (const float*)d_in[23];
    const float* hb2      = (const float*)d_in[24];
    const float* hw3      = (const float*)d_in[25];
    const float* hb3      = (const float*)d_in[26];

    const int E = N_EDGES;
    const int* srcI = eidx;
    const int* dstI = eidx + E;

    char* w = (char*)d_ws;
    auto carve = [&](size_t bytes) -> void* {
        void* p = (void*)w;
        w += (bytes + 255) & ~(size_t)255;
        return p;
    };
    float* U1    = (float*)carve((size_t)3072 * 1800 * 4);
    float* P     = (float*)carve((size_t)3072 * 900 * 4);
    float* Hbuf  = (float*)carve((size_t)3072 * 300 * 4);
    float* hF    = (float*)carve((size_t)3072 * 300 * 4);
    float* W3eff = (float*)carve((size_t)2 * 1800 * 4);
    float* cb    = (float*)carve((size_t)1800 * 4);
    float* degc  = (float*)carve((size_t)3072 * 4);
    float* amp   = (float*)carve((size_t)3072 * 4);
    float* att   = (float*)carve((size_t)3072 * 4);
    float* avgp  = (float*)carve(256);
    float* gpool = (float*)carve((size_t)16 * 300 * 4);
    float* g1    = (float*)carve((size_t)16 * 600 * 4);
    float* g2    = (float*)carve((size_t)16 * 300 * 4);
    float* part  = (float*)carve((size_t)POOL_S * 16 * 300 * 4);
    float2* eag  = (float2*)carve((size_t)E * 8);
    int* deg = (int*)carve((size_t)3072 * 4);
    int* off = (int*)carve((size_t)3073 * 4);
    int* cur = (int*)carve((size_t)3072 * 4);
    int* ce  = (int*)carve((size_t)E * 4);
    int* gs  = (int*)carve((size_t)E * 4);

    u16* u2bf    = (u16*)carve((size_t)3072 * 1800 * 2);
    u16* xbf_h   = (u16*)carve((size_t)3072 * 32 * 2);
    u16* xbf_l   = (u16*)carve((size_t)3072 * 32 * 2);
    u16* hbf_h   = (u16*)carve((size_t)3072 * 320 * 2);
    u16* hbf_l   = (u16*)carve((size_t)3072 * 320 * 2);
    u16* pbf_h   = (u16*)carve((size_t)3072 * 320 * 2);
    u16* pbf_l   = (u16*)carve((size_t)3072 * 320 * 2);
    u16* agg_h   = (u16*)carve((size_t)18432 * 1216 * 2);
    u16* Wu0A_h  = (u16*)carve((size_t)704 * 32 * 2);
    u16* Wu0A_l  = (u16*)carve((size_t)704 * 32 * 2);
    u16* WuA_h   = (u16*)carve((size_t)4 * 4096 * 320 * 2);
    u16* WuA_l   = (u16*)carve((size_t)4 * 4096 * 320 * 2);
    u16* Wp0T_h  = (u16*)carve((size_t)6 * 192 * 128 * 2);
    u16* WpT_h   = (u16*)carve((size_t)24 * 192 * 1216 * 2);
    u16* linT_h  = (u16*)carve((size_t)5 * 320 * 320 * 2);
    u16* linT_l  = (u16*)carve((size_t)5 * 320 * 320 * 2);

    // ---- setup ----
    zero_int_k<<<(3072 + 255) / 256, 256, 0, stream>>>(deg, 3072);
    count_deg_k<<<(E + 255) / 256, 256, 0, stream>>>(dstI, deg, E);
    scan_off_k<<<1, 1024, 0, stream>>>(deg, off);
    init_cur_k<<<(3072 + 255) / 256, 256, 0, stream>>>(off, cur, 3072);
    scatter_k<<<(E + 255) / 256, 256, 0, stream>>>(dstI, cur, ce, E);
    gather_idx_k<<<(E + 255) / 256, 256, 0, stream>>>(ce, srcI, eattr, gs, eag, E);
    avg_log_k<<<1, 64, 0, stream>>>(deg_hist, avgp);
    node_scalers_k<<<(3072 + 255) / 256, 256, 0, stream>>>(deg, avgp, degc, amp, att, 3072);

    // ---- conversions ----
    cvt_x_k<<<(3072 * 32 + 255) / 256, 256, 0, stream>>>(x, xbf_h, xbf_l);
    cvt_wu0_k<<<dim3((192 * 32 + 255) / 256, 1, 2), 256, 0, stream>>>(prew0, Wu0A_h, Wu0A_l);
    cvt_wh0_k<<<(320 * 32 + 255) / 256, 256, 0, stream>>>(postw0, Wu0A_h + 384 * 32, Wu0A_l + 384 * 32);
    cvt_wp0_k<<<dim3((192 * 128 + 255) / 256, 1, 6), 256, 0, stream>>>(postw0, Wp0T_h);
    cvt_tr_k<<<dim3(5, 5, 48), 256, 0, stream>>>(prew, WuA_h, WuA_l, 2, 6,
        1620000LL, 90000LL, 270000LL, 0LL, 1310720LL, 593920LL, 96000LL, 300, 300, 300, 320);
    cvt_tr_k<<<dim3(5, 1, 24), 256, 0, stream>>>(postw, WuA_h + 1187840, WuA_l + 1187840, 1, 6,
        1170000LL, 0LL, 195000LL, 0LL, 1310720LL, 0LL, 16000LL, 300, 50, 50, 320);
    cvt_tr_k<<<dim3(19, 1, 72), 256, 0, stream>>>(postw, WpT_h, nullptr, 6, 3,
        1170000LL, 195000LL, 60000LL, 15000LL, 1400832LL, 233472LL, 60800LL, 1200, 50, 50, 1216);
    cvt_tr_k<<<dim3(5, 5, 1), 256, 0, stream>>>(linw0, linT_h, linT_l, 1, 1,
        0LL, 0LL, 0LL, 0LL, 0LL, 0LL, 0LL, 300, 300, 300, 320);
    cvt_tr_k<<<dim3(5, 5, 4), 256, 0, stream>>>(linw, linT_h + 102400, linT_l + 102400, 1, 1,
        90000LL, 0LL, 0LL, 0LL, 102400LL, 0LL, 0LL, 300, 300, 300, 320);

    // ---- layer 0 (Fh=32, TF=192) ----
    {
        zero3_k<<<(3 * 192 + 255) / 256, 256, 0, stream>>>(W3eff, cb, 192);
        prep_edge2_k<<<dim3(1, 3, KC_PREP), 256, 0, stream>>>(
            ew0, eb0, prew0, preb0, W3eff, cb, 32, 192);
        mfma_fu_k<<<dim3(24, 11), 256, 0, stream>>>(
            xbf_h, xbf_l, 32, Wu0A_h, Wu0A_l, 32, 32, cb,
            U1, 192, u2bf, 192, Hbuf, 300, 192, 384, 192, 300);
        // QC = ceil(24/8) = 3 -> grid = 8 * 1 * 96
        agg_k<<<8 * 1 * 96, 256, 0, stream>>>(
            U1, u2bf, W3eff, off, gs, eag, degc, agg_h, 32, 192, 192, 3);
        mfma_gemm_t<1, 1, 64><<<dim3(48, 3, 6), 256, 0, stream>>>(
            agg_h, nullptr, 7296, 1216, Wp0T_h, nullptr, 128, 192 * 128, 128, nullptr,
            P, 900, 150, 150, 0, nullptr, nullptr, 0, 0);
        combine_k<<<((size_t)3072 * 300 + 255) / 256, 256, 0, stream>>>(
            Hbuf, P, amp, att, postb0, pbf_h, pbf_l);
        mfma_gemm_t<0, 0, 64><<<dim3(48, 5), 256, 0, stream>>>(
            pbf_h, pbf_l, 320, 0, linT_h, linT_l, 320, 0, 320, linb0,
            hF, 300, 0, 300, 1, hbf_h, hbf_l, 320, 0);
    }

    // ---- layers 1..4 ----
    for (int l = 0; l < N_INNER; l++) {
        zero3_k<<<(3 * 1800 + 255) / 256, 256, 0, stream>>>(W3eff, cb, 1800);
        prep_edge2_k<<<dim3(8, 3, KC_PREP), 256, 0, stream>>>(
            ew + (size_t)l * 600, eb + (size_t)l * 300,
            prew + (size_t)l * 6 * 900 * 300, preb + (size_t)l * 6 * 300, W3eff, cb, 300, 1800);
        mfma_fu_k<<<dim3(24, 63), 256, 0, stream>>>(
            hbf_h, hbf_l, 320,
            WuA_h + (size_t)l * 1310720, WuA_l + (size_t)l * 1310720, 320, 320, cb,
            U1, 1800, u2bf, 1800, Hbuf, 300, 1856, 3712, 1800, 300);
        // QC = ceil(225/8) = 29 -> grid = 8 * 4 * 96
        agg_k<<<8 * 4 * 96, 256, 0, stream>>>(
            U1, u2bf, W3eff, off, gs, eag, degc, agg_h, 300, 1800, 1800, 29);
        mfma_gemm_t<1, 1, 64><<<dim3(48, 3, 6), 256, 0, stream>>>(
            agg_h, nullptr, 7296, 1216,
            WpT_h + (size_t)l * 6 * 192 * 1216, nullptr, 1216, 192 * 1216, 1216, nullptr,
            P, 900, 150, 150, 0, nullptr, nullptr, 0, 0);
        combine_k<<<((size_t)3072 * 300 + 255) / 256, 256, 0, stream>>>(
            Hbuf, P, amp, att, postb + (size_t)l * 300, pbf_h, pbf_l);
        int relu = (l < N_INNER - 1) ? 1 : 0;
        mfma_gemm_t<0, 0, 64><<<dim3(48, 5), 256, 0, stream>>>(
            pbf_h, pbf_l, 320, 0,
            linT_h + (size_t)(l + 1) * 102400, linT_l + (size_t)(l + 1) * 102400, 320, 0,
            320, linb + (size_t)l * 300, hF, 300, 0, 300, relu, hbf_h, hbf_l, 320, 0);
    }

    // ---- head ----
    pool_part_k<<<(POOL_S * 16 * 300 + 255) / 256, 256, 0, stream>>>(hF, part);
    pool_red_k<<<(16 * 300 + 255) / 256, 256, 0, stream>>>(part, gpool);
    fc_wave_k<<<((size_t)16 * 600 * 64 + 255) / 256, 256, 0, stream>>>(
        gpool, hw1, hb1, g1, 16, 300, 600, 1);
    fc_wave_k<<<((size_t)16 * 300 * 64 + 255) / 256, 256, 0, stream>>>(
        g1, hw2, hb2, g2, 16, 600, 300, 1);
    fc_wave_k<<<(16 * 64 + 255) / 256, 256, 0, stream>>>(
        g2, hw3, hb3, (float*)d_out, 16, 300, 1, 1);
}

// Round 10
// 771.607 us; speedup vs baseline: 1.0534x; 1.0534x over previous
//
#include <hip/hip_runtime.h>
#include <hip/hip_bf16.h>
#include <math.h>

#define N_NODES 3072
#define N_EDGES 30720
#define G_GRAPHS 16
#define IN_DIM 32
#define EMB 300
#define T_TOWERS 6
#define F_OUT 50
#define N_INNER 4
#define EPS_V 1e-5f
#define POOL_S 8
#define KC_PREP 10

typedef unsigned short u16;
typedef __attribute__((ext_vector_type(8))) unsigned short u16x8;
typedef __attribute__((ext_vector_type(4))) unsigned short u16x4;
typedef __attribute__((ext_vector_type(8))) short bf16x8;
typedef __attribute__((ext_vector_type(4))) float f32x4;

__device__ inline u16 f2bf(float v) {
    union { float f; unsigned u; } x; x.f = v;
    unsigned r = x.u + 0x7FFF + ((x.u >> 16) & 1);
    return (u16)(r >> 16);
}
__device__ inline float bf2f(u16 h) {
    union { unsigned u; float f; } x; x.u = ((unsigned)h) << 16;
    return x.f;
}
__device__ inline void split2(float v, u16* ph, u16* pl) {
    u16 h = f2bf(v);
    *ph = h;
    *pl = f2bf(v - bf2f(h));
}

// ---------------- setup kernels ----------------

__global__ void zero_int_k(int* p, int n) {
    int i = blockIdx.x * blockDim.x + threadIdx.x;
    if (i < n) p[i] = 0;
}

__global__ void count_deg_k(const int* __restrict__ dst, int* __restrict__ deg, int e_cnt) {
    int e = blockIdx.x * blockDim.x + threadIdx.x;
    if (e < e_cnt) atomicAdd(&deg[dst[e]], 1);
}

__global__ void scan_off_k(const int* __restrict__ deg, int* __restrict__ off) {
    __shared__ int sums[1024];
    int tid = threadIdx.x;
    int base = tid * 3;
    int v0 = deg[base], v1 = deg[base + 1], v2 = deg[base + 2];
    int s = v0 + v1 + v2;
    sums[tid] = s;
    __syncthreads();
    for (int d = 1; d < 1024; d <<= 1) {
        int x = (tid >= d) ? sums[tid - d] : 0;
        __syncthreads();
        sums[tid] += x;
        __syncthreads();
    }
    int excl = sums[tid] - s;
    off[base] = excl;
    off[base + 1] = excl + v0;
    off[base + 2] = excl + v0 + v1;
    if (tid == 1023) off[N_NODES] = sums[1023];
}

__global__ void init_cur_k(const int* __restrict__ off, int* __restrict__ cur, int n) {
    int i = blockIdx.x * blockDim.x + threadIdx.x;
    if (i < n) cur[i] = off[i];
}

__global__ void scatter_k(const int* __restrict__ dst, int* __restrict__ cur,
                          int* __restrict__ ce, int e_cnt) {
    int e = blockIdx.x * blockDim.x + threadIdx.x;
    if (e < e_cnt) {
        int p = atomicAdd(&cur[dst[e]], 1);
        ce[p] = e;
    }
}

__global__ void gather_idx_k(const int* __restrict__ ce, const int* __restrict__ srcI,
                             const float* __restrict__ ea,
                             int* __restrict__ gs, float2* __restrict__ eag, int e_cnt) {
    int p = blockIdx.x * blockDim.x + threadIdx.x;
    if (p < e_cnt) {
        int e = ce[p];
        gs[p] = srcI[e];
        eag[p] = make_float2(ea[2 * e], ea[2 * e + 1]);
    }
}

__global__ void avg_log_k(const float* __restrict__ hist, float* __restrict__ out) {
    __shared__ float a[64], b[64];
    int i = threadIdx.x;
    float l = logf((float)i + 1.0f);
    a[i] = l * hist[i];
    b[i] = hist[i];
    __syncthreads();
    if (i == 0) {
        float sa = 0.f, sb = 0.f;
        for (int j = 0; j < 64; j++) { sa += a[j]; sb += b[j]; }
        out[0] = sa / sb;
    }
}

__global__ void node_scalers_k(const int* __restrict__ deg, const float* __restrict__ avg,
                               float* __restrict__ degc, float* __restrict__ amp,
                               float* __restrict__ att, int n) {
    int i = blockIdx.x * blockDim.x + threadIdx.x;
    if (i < n) {
        float d = fmaxf((float)deg[i], 1.0f);
        degc[i] = d;
        float lg = logf(d + 1.0f);
        float al = avg[0];
        amp[i] = lg / al;
        att[i] = al / lg;
    }
}

// ---------------- per-layer edge-weight prep ----------------
__global__ void zero3_k(float* __restrict__ W3eff, float* __restrict__ cb, int TF) {
    int i = blockIdx.x * blockDim.x + threadIdx.x;
    if (i < 2 * TF) W3eff[i] = 0.f;
    else if (i < 3 * TF) cb[i - 2 * TF] = 0.f;
}

__global__ void prep_edge2_k(const float* __restrict__ ew, const float* __restrict__ eb,
                             const float* __restrict__ prew, const float* __restrict__ preb,
                             float* __restrict__ W3eff, float* __restrict__ cb,
                             int Fh, int TF) {
    int tf = blockIdx.x * 256 + threadIdx.x;
    if (tf >= TF) return;
    int j = blockIdx.y, kc = blockIdx.z;
    int chunk = (Fh + KC_PREP - 1) / KC_PREP;
    int k0 = kc * chunk, k1 = min(k0 + chunk, Fh);
    if (k0 >= Fh) return;
    int t = tf / Fh, f = tf - t * Fh;
    const float* col = prew + ((size_t)t * 3 * Fh + 2 * Fh) * Fh + f;
    const float* vec = (j < 2) ? (ew + (size_t)j * Fh) : eb;
    float s = 0.f;
    for (int k = k0; k < k1; k++) s += vec[k] * col[(size_t)k * Fh];
    if (j < 2) atomicAdd(&W3eff[(size_t)j * TF + tf], s);
    else {
        if (kc == 0) s += preb[(size_t)t * Fh + f];
        atomicAdd(&cb[tf], s);
    }
}

// ---------------- generic LDS-tiled transpose + split (dl optional) ----------------
__global__ void cvt_tr_k(const float* __restrict__ src, u16* __restrict__ dh, u16* __restrict__ dl,
                         int F2, int F3,
                         long long s1, long long s2, long long s3, long long soff,
                         long long d1, long long d2, long long d3,
                         int R, int C, int sRow, int dRow) {
    __shared__ float tile[64][65];
    int z = blockIdx.z;
    int c3 = z % F3; int zz = z / F3; int c2 = zz % F2; int c1 = zz / F2;
    src += c1 * s1 + c2 * s2 + c3 * s3 + soff;
    long long doff = c1 * d1 + c2 * d2 + c3 * d3;
    dh += doff; if (dl) dl += doff;
    int r0 = blockIdx.x * 64, c0 = blockIdx.y * 64;
    int tx = threadIdx.x & 63, ty = threadIdx.x >> 6;
#pragma unroll
    for (int i = 0; i < 64; i += 4) {
        int r = r0 + ty + i, c = c0 + tx;
        tile[ty + i][tx] = (r < R && c < C) ? src[(size_t)r * sRow + c] : 0.f;
    }
    __syncthreads();
#pragma unroll
    for (int i = 0; i < 64; i += 4) {
        int c = c0 + ty + i, r = r0 + tx;
        if (c < C && r < dRow) {
            float v = tile[tx][ty + i];
            u16 h = f2bf(v);
            dh[(size_t)c * dRow + r] = h;
            if (dl) dl[(size_t)c * dRow + r] = f2bf(v - bf2f(h));
        }
    }
}

// ---------------- layer-0 (tiny) conversions ----------------
__global__ void cvt_wu0_k(const float* __restrict__ prew0, u16* __restrict__ Wh, u16* __restrict__ Wl) {
    int p = blockIdx.z;
    int idx = blockIdx.x * 256 + threadIdx.x;
    if (idx >= 192 * 32) return;
    int n = idx / 32, k = idx - n * 32;
    int t = n / 32, f = n - t * 32;
    float v = prew0[((size_t)t * 96 + p * 32 + k) * 32 + f];
    size_t o = (size_t)p * 192 * 32 + idx;
    split2(v, &Wh[o], &Wl[o]);
}

__global__ void cvt_wh0_k(const float* __restrict__ postw0, u16* __restrict__ Wh, u16* __restrict__ Wl) {
    int idx = blockIdx.x * 256 + threadIdx.x;
    if (idx >= 320 * 32) return;
    int n = idx / 32, k = idx - n * 32;
    float v = 0.f;
    if (n < 300) {
        int t = n / 50, j = n - t * 50;
        v = postw0[((size_t)t * 416 + k) * 50 + j];
    }
    split2(v, &Wh[idx], &Wl[idx]);
}

__global__ void cvt_wp0_k(const float* __restrict__ postw0, u16* __restrict__ Wh) {
    int t = blockIdx.z;
    int idx = blockIdx.x * 256 + threadIdx.x;
    if (idx >= 192 * 128) return;
    int gn = idx / 128, k = idx - gn * 128;
    if (gn >= 150) return;
    int s = gn / 50, j = gn - s * 50;
    float v = postw0[((size_t)t * 416 + 32 + s * 128 + k) * 50 + j];
    Wh[(size_t)t * 192 * 128 + idx] = f2bf(v);
}

__global__ void cvt_x_k(const float* __restrict__ x, u16* __restrict__ Xh, u16* __restrict__ Xl) {
    int idx = blockIdx.x * 256 + threadIdx.x;
    if (idx >= 3072 * 32) return;
    split2(x[idx], &Xh[idx], &Xl[idx]);
}

// swizzled LDS slot: 16B-slot s at row r lives at physical slot s ^ ((r>>1)&3)
#define SWZ(row, s) (((s) ^ (((row) >> 1) & 3)) << 3)

// ---------------- fused U1+U2+H GEMM (A,B hi/lo split, 3-MFMA, prefetch, swizzle) ----
// U1 now written as bf16 (u16), like U2.
__global__ __launch_bounds__(256)
void mfma_fu_k(const u16* __restrict__ Ah, const u16* __restrict__ Al, int lda,
               const u16* __restrict__ Bh, const u16* __restrict__ Bl, int ldb,
               int K, const float* __restrict__ cb,
               u16* __restrict__ U1, int ldu1,
               u16* __restrict__ U2, int ldu2,
               float* __restrict__ Hout, int ldh,
               int us1, int us2, int N1, int NH) {
    __shared__ u16 As_h[128][32], As_l[128][32], Bs_h[64][32], Bs_l[64][32];
    const int tid = threadIdx.x;
    const int wave = tid >> 6, lane = tid & 63;
    const int wr = wave >> 1, wc = wave & 1;
    const int fr = lane & 15, fkb = lane >> 4;
    const int m0 = blockIdx.x * 128, n0 = blockIdx.y * 64;
    const int srow = tid >> 2, sc = tid & 3, sk = sc * 8;
    const int wsk = SWZ(srow, sc);
    const u16* pa0h = Ah + (size_t)(m0 + srow) * lda + sk;
    const u16* pa1h = Ah + (size_t)(m0 + 64 + srow) * lda + sk;
    const u16* pa0l = Al + (size_t)(m0 + srow) * lda + sk;
    const u16* pa1l = Al + (size_t)(m0 + 64 + srow) * lda + sk;
    const u16* pb0h = Bh + (size_t)(n0 + srow) * ldb + sk;
    const u16* pb0l = Bl + (size_t)(n0 + srow) * ldb + sk;
    u16x8 a0h = *(const u16x8*)pa0h;
    u16x8 a1h = *(const u16x8*)pa1h;
    u16x8 a0l = *(const u16x8*)pa0l;
    u16x8 a1l = *(const u16x8*)pa1l;
    u16x8 b0h = *(const u16x8*)pb0h;
    u16x8 b0l = *(const u16x8*)pb0l;

    f32x4 acc[4][2];
#pragma unroll
    for (int i = 0; i < 4; i++)
#pragma unroll
        for (int j = 0; j < 2; j++) acc[i][j] = (f32x4){0.f, 0.f, 0.f, 0.f};

    for (int k0 = 0; k0 < K; k0 += 32) {
        __syncthreads();
        *(u16x8*)&As_h[srow][wsk] = a0h;
        *(u16x8*)&As_h[64 + srow][wsk] = a1h;
        *(u16x8*)&As_l[srow][wsk] = a0l;
        *(u16x8*)&As_l[64 + srow][wsk] = a1l;
        *(u16x8*)&Bs_h[srow][wsk] = b0h;
        *(u16x8*)&Bs_l[srow][wsk] = b0l;
        __syncthreads();
        int kn = k0 + 32;
        if (kn < K) {
            a0h = *(const u16x8*)(pa0h + kn);
            a1h = *(const u16x8*)(pa1h + kn);
            a0l = *(const u16x8*)(pa0l + kn);
            a1l = *(const u16x8*)(pa1l + kn);
            b0h = *(const u16x8*)(pb0h + kn);
            b0l = *(const u16x8*)(pb0l + kn);
        }
        bf16x8 ah[4], al[4], bh[2], bl[2];
#pragma unroll
        for (int i = 0; i < 4; i++) {
            int ar = wr * 64 + i * 16 + fr;
            ah[i] = *(const bf16x8*)&As_h[ar][SWZ(ar, fkb)];
            al[i] = *(const bf16x8*)&As_l[ar][SWZ(ar, fkb)];
        }
#pragma unroll
        for (int j = 0; j < 2; j++) {
            int br = wc * 32 + j * 16 + fr;
            bh[j] = *(const bf16x8*)&Bs_h[br][SWZ(br, fkb)];
            bl[j] = *(const bf16x8*)&Bs_l[br][SWZ(br, fkb)];
        }
#pragma unroll
        for (int i = 0; i < 4; i++)
#pragma unroll
            for (int j = 0; j < 2; j++) {
                acc[i][j] = __builtin_amdgcn_mfma_f32_16x16x32_bf16(ah[i], bh[j], acc[i][j], 0, 0, 0);
                acc[i][j] = __builtin_amdgcn_mfma_f32_16x16x32_bf16(ah[i], bl[j], acc[i][j], 0, 0, 0);
                acc[i][j] = __builtin_amdgcn_mfma_f32_16x16x32_bf16(al[i], bh[j], acc[i][j], 0, 0, 0);
            }
    }
#pragma unroll
    for (int i = 0; i < 4; i++)
#pragma unroll
        for (int j = 0; j < 2; j++) {
            int col = n0 + wc * 32 + j * 16 + fr;
            int rowb = m0 + wr * 64 + i * 16 + fkb * 4;
            if (col < us1) {
                if (col < N1) {
                    float bv = cb[col];
#pragma unroll
                    for (int r = 0; r < 4; r++)
                        U1[(size_t)(rowb + r) * ldu1 + col] = f2bf(acc[i][j][r] + bv);
                }
            } else if (col < us2) {
                int ec = col - us1;
                if (ec < N1) {
#pragma unroll
                    for (int r = 0; r < 4; r++)
                        U2[(size_t)(rowb + r) * ldu2 + ec] = f2bf(acc[i][j][r]);
                }
            } else {
                int ec = col - us2;
                if (ec < NH) {
#pragma unroll
                    for (int r = 0; r < 4; r++)
                        Hout[(size_t)(rowb + r) * ldh + ec] = acc[i][j][r];
                }
            }
        }
}

// ---------------- generic MFMA GEMM (templated splits + tile M, prefetch, swizzle) ----
template<int ASINGLE, int BSINGLE, int TM>
__global__ __launch_bounds__(256)
void mfma_gemm_t(const u16* __restrict__ Ah, const u16* __restrict__ Al, int lda, int aZstr,
                 const u16* __restrict__ Bh, const u16* __restrict__ Bl, int ldb, int bZstr,
                 int K, const float* __restrict__ bias,
                 float* __restrict__ C, int ldc, int cZstr, int Nout, int relu,
                 u16* __restrict__ C2h, u16* __restrict__ C2l, int ldc2, int c2Zstr) {
    constexpr int MI = TM / 32;
    constexpr int AR = TM / 64;
    __shared__ u16 As_h[TM][32];
    __shared__ u16 As_l[ASINGLE ? 1 : TM][32];
    __shared__ u16 Bs_h[64][32];
    __shared__ u16 Bs_l[BSINGLE ? 1 : 64][32];
    const int z = blockIdx.z;
    Ah += (size_t)z * aZstr;
    if (!ASINGLE) Al += (size_t)z * aZstr;
    Bh += (size_t)z * bZstr;
    if (!BSINGLE) Bl += (size_t)z * bZstr;
    if (C) C += (size_t)z * cZstr;
    if (C2h) C2h += (size_t)z * c2Zstr;
    if (C2l) C2l += (size_t)z * c2Zstr;
    const int tid = threadIdx.x;
    const int wave = tid >> 6, lane = tid & 63;
    const int wr = wave >> 1, wc = wave & 1;
    const int fr = lane & 15, fkb = lane >> 4;
    const int m0 = blockIdx.x * TM, n0 = blockIdx.y * 64;
    const int srow = tid >> 2, sc = tid & 3, sk = sc * 8;
    const int wsk = SWZ(srow, sc);

    u16x8 rah[AR], ral[ASINGLE ? 1 : AR], rbh, rbl;
#pragma unroll
    for (int ii = 0; ii < AR; ii++) {
        rah[ii] = *(const u16x8*)(Ah + (size_t)(m0 + ii * 64 + srow) * lda + sk);
        if (!ASINGLE) ral[ii] = *(const u16x8*)(Al + (size_t)(m0 + ii * 64 + srow) * lda + sk);
    }
    rbh = *(const u16x8*)(Bh + (size_t)(n0 + srow) * ldb + sk);
    if (!BSINGLE) rbl = *(const u16x8*)(Bl + (size_t)(n0 + srow) * ldb + sk);

    f32x4 acc[MI][2];
#pragma unroll
    for (int i = 0; i < MI; i++)
#pragma unroll
        for (int j = 0; j < 2; j++) acc[i][j] = (f32x4){0.f, 0.f, 0.f, 0.f};

    for (int k0 = 0; k0 < K; k0 += 32) {
        __syncthreads();
#pragma unroll
        for (int ii = 0; ii < AR; ii++) {
            *(u16x8*)&As_h[ii * 64 + srow][wsk] = rah[ii];
            if (!ASINGLE) *(u16x8*)&As_l[ii * 64 + srow][wsk] = ral[ii];
        }
        *(u16x8*)&Bs_h[srow][wsk] = rbh;
        if (!BSINGLE) *(u16x8*)&Bs_l[srow][wsk] = rbl;
        __syncthreads();
        int kn = k0 + 32;
        if (kn < K) {
#pragma unroll
            for (int ii = 0; ii < AR; ii++) {
                rah[ii] = *(const u16x8*)(Ah + (size_t)(m0 + ii * 64 + srow) * lda + kn + sk);
                if (!ASINGLE) ral[ii] = *(const u16x8*)(Al + (size_t)(m0 + ii * 64 + srow) * lda + kn + sk);
            }
            rbh = *(const u16x8*)(Bh + (size_t)(n0 + srow) * ldb + kn + sk);
            if (!BSINGLE) rbl = *(const u16x8*)(Bl + (size_t)(n0 + srow) * ldb + kn + sk);
        }
        bf16x8 ah[MI], al[MI], bh[2], bl[2];
#pragma unroll
        for (int i = 0; i < MI; i++) {
            int ar = wr * (TM / 2) + i * 16 + fr;
            ah[i] = *(const bf16x8*)&As_h[ar][SWZ(ar, fkb)];
            if (!ASINGLE) al[i] = *(const bf16x8*)&As_l[ar][SWZ(ar, fkb)];
        }
#pragma unroll
        for (int j = 0; j < 2; j++) {
            int br = wc * 32 + j * 16 + fr;
            bh[j] = *(const bf16x8*)&Bs_h[br][SWZ(br, fkb)];
            if (!BSINGLE) bl[j] = *(const bf16x8*)&Bs_l[br][SWZ(br, fkb)];
        }
#pragma unroll
        for (int i = 0; i < MI; i++)
#pragma unroll
            for (int j = 0; j < 2; j++) {
                acc[i][j] = __builtin_amdgcn_mfma_f32_16x16x32_bf16(ah[i], bh[j], acc[i][j], 0, 0, 0);
                if (!BSINGLE)
                    acc[i][j] = __builtin_amdgcn_mfma_f32_16x16x32_bf16(ah[i], bl[j], acc[i][j], 0, 0, 0);
                if (!ASINGLE)
                    acc[i][j] = __builtin_amdgcn_mfma_f32_16x16x32_bf16(al[i], bh[j], acc[i][j], 0, 0, 0);
            }
    }
#pragma unroll
    for (int i = 0; i < MI; i++)
#pragma unroll
        for (int j = 0; j < 2; j++) {
            int col = n0 + wc * 32 + j * 16 + fr;
            if (col < Nout) {
                float bv = bias ? bias[col] : 0.f;
                int rowb = m0 + wr * (TM / 2) + i * 16 + fkb * 4;
#pragma unroll
                for (int r = 0; r < 4; r++) {
                    float v = acc[i][j][r] + bv;
                    if (relu) v = fmaxf(v, 0.f);
                    if (C) C[(size_t)(rowb + r) * ldc + col] = v;
                    if (C2h) {
                        if (C2l) split2(v, &C2h[(size_t)(rowb + r) * ldc2 + col],
                                           &C2l[(size_t)(rowb + r) * ldc2 + col]);
                        else C2h[(size_t)(rowb + r) * ldc2 + col] = f2bf(v);
                    }
                }
            }
        }
}

// ---------------- aggregation (node-major, U1/U2 bf16, 8 feats/thread, unroll-2) ----
__global__ void agg_k(const u16* __restrict__ U1, const u16* __restrict__ U2,
                      const float* __restrict__ W3eff,
                      const int* __restrict__ off, const int* __restrict__ gs,
                      const float2* __restrict__ eag, const float* __restrict__ degc,
                      u16* __restrict__ agg_h, int Fh, int TF, int u2ld) {
    int idx = blockIdx.x * blockDim.x + threadIdx.x;
    int nt = TF >> 3;
    if (idx >= N_NODES * nt) return;
    int n = idx / nt, q = idx - n * nt;
    int tf = q << 3;
    float w0[8], w1[8], cc[8];
    *(float4*)&w0[0] = *(const float4*)(W3eff + tf);
    *(float4*)&w0[4] = *(const float4*)(W3eff + tf + 4);
    *(float4*)&w1[0] = *(const float4*)(W3eff + TF + tf);
    *(float4*)&w1[4] = *(const float4*)(W3eff + TF + tf + 4);
    {
        u16x8 c8 = *(const u16x8*)(U1 + (size_t)n * u2ld + tf);
#pragma unroll
        for (int r = 0; r < 8; r++) cc[r] = bf2f(c8[r]);
    }
    int beg = off[n], end = off[n + 1];
    float s1[8], s2[8], mn[8], mx[8];
#pragma unroll
    for (int r = 0; r < 8; r++) { s1[r] = 0.f; s2[r] = 0.f; mn[r] = INFINITY; mx[r] = -INFINITY; }
    int p = beg;
    for (; p + 1 < end; p += 2) {
        int sa = gs[p], sb = gs[p + 1];
        float2 ea0 = eag[p], ea1 = eag[p + 1];
        u16x8 ra = *(const u16x8*)(U2 + (size_t)sa * u2ld + tf);
        u16x8 rb = *(const u16x8*)(U2 + (size_t)sb * u2ld + tf);
#pragma unroll
        for (int r = 0; r < 8; r++) {
            float va = bf2f(ra[r]) + ea0.x * w0[r] + ea0.y * w1[r];
            s1[r] += va; s2[r] += va * va;
            mn[r] = fminf(mn[r], va); mx[r] = fmaxf(mx[r], va);
            float vb = bf2f(rb[r]) + ea1.x * w0[r] + ea1.y * w1[r];
            s1[r] += vb; s2[r] += vb * vb;
            mn[r] = fminf(mn[r], vb); mx[r] = fmaxf(mx[r], vb);
        }
    }
    if (p < end) {
        int sa = gs[p];
        float2 ea0 = eag[p];
        u16x8 ra = *(const u16x8*)(U2 + (size_t)sa * u2ld + tf);
#pragma unroll
        for (int r = 0; r < 8; r++) {
            float va = bf2f(ra[r]) + ea0.x * w0[r] + ea0.y * w1[r];
            s1[r] += va; s2[r] += va * va;
            mn[r] = fminf(mn[r], va); mx[r] = fmaxf(mx[r], va);
        }
    }
    float dc = degc[n];
    u16 o0[8], o1[8], o2[8], o3[8];
#pragma unroll
    for (int r = 0; r < 8; r++) {
        float mean = s1[r] / dc;
        float var = fmaxf(s2[r] / dc - mean * mean, 0.f);
        float sd = sqrtf(var + EPS_V);
        o0[r] = f2bf(mean + cc[r]);
        o1[r] = f2bf(mn[r] + cc[r]);
        o2[r] = f2bf(mx[r] + cc[r]);
        o3[r] = f2bf(sd);
    }
    int t0 = tf / Fh, f0 = tf - t0 * Fh;
    if (f0 + 8 <= Fh) {
        size_t base = ((size_t)n * 6 + t0) * 1216 + f0;
        *(u16x4*)(agg_h + base) = *(u16x4*)&o0[0];
        *(u16x4*)(agg_h + base + 4) = *(u16x4*)&o0[4];
        *(u16x4*)(agg_h + base + Fh) = *(u16x4*)&o1[0];
        *(u16x4*)(agg_h + base + Fh + 4) = *(u16x4*)&o1[4];
        *(u16x4*)(agg_h + base + 2 * Fh) = *(u16x4*)&o2[0];
        *(u16x4*)(agg_h + base + 2 * Fh + 4) = *(u16x4*)&o2[4];
        *(u16x4*)(agg_h + base + 3 * Fh) = *(u16x4*)&o3[0];
        *(u16x4*)(agg_h + base + 3 * Fh + 4) = *(u16x4*)&o3[4];
    } else {
#pragma unroll
        for (int r = 0; r < 8; r++) {
            int tfr = tf + r;
            int t = tfr / Fh, f = tfr - t * Fh;
            size_t base = ((size_t)n * 6 + t) * 1216 + f;
            agg_h[base] = o0[r];
            agg_h[base + Fh] = o1[r];
            agg_h[base + 2 * Fh] = o2[r];
            agg_h[base + 3 * Fh] = o3[r];
        }
    }
}

// ---------------- combine ----------------
__global__ void combine_k(const float* __restrict__ H, const float* __restrict__ P,
                          const float* __restrict__ amp, const float* __restrict__ att,
                          const float* __restrict__ postb,
                          u16* __restrict__ ph, u16* __restrict__ pl) {
    int idx = blockIdx.x * blockDim.x + threadIdx.x;
    if (idx >= N_NODES * EMB) return;
    int n = idx / EMB, tf = idx - n * EMB;
    int t = tf / F_OUT, j = tf - t * F_OUT;
    const float* Pr = P + (size_t)n * 900 + t * 150;
    float v = H[idx] + Pr[j] + amp[n] * Pr[F_OUT + j] + att[n] * Pr[2 * F_OUT + j]
            + postb[(size_t)t * F_OUT + j];
    split2(v, &ph[(size_t)n * 320 + tf], &pl[(size_t)n * 320 + tf]);
}

// ---------------- head ----------------

__global__ void pool_part_k(const float* __restrict__ h, float* __restrict__ part) {
    int idx = blockIdx.x * blockDim.x + threadIdx.x;
    if (idx >= POOL_S * G_GRAPHS * EMB) return;
    int s = idx / (G_GRAPHS * EMB), rem = idx - s * (G_GRAPHS * EMB);
    int g = rem / EMB, f = rem - g * EMB;
    const int per = N_NODES / G_GRAPHS;
    const int chunk = per / POOL_S;
    int r0 = g * per + s * chunk;
    float acc = 0.f;
#pragma unroll
    for (int i = 0; i < 24; i++) acc += h[(size_t)(r0 + i) * EMB + f];
    part[idx] = acc;
}

__global__ void pool_red_k(const float* __restrict__ part, float* __restrict__ gpool) {
    int idx = blockIdx.x * blockDim.x + threadIdx.x;
    if (idx >= G_GRAPHS * EMB) return;
    float s = 0.f;
#pragma unroll
    for (int i = 0; i < POOL_S; i++) s += part[(size_t)i * G_GRAPHS * EMB + idx];
    gpool[idx] = s;
}

__global__ void fc_wave_k(const float* __restrict__ A, const float* __restrict__ W,
                          const float* __restrict__ b, float* __restrict__ out,
                          int M, int K, int Nout, int relu) {
    int gw = (blockIdx.x * blockDim.x + threadIdx.x) >> 6;
    int lane = threadIdx.x & 63;
    if (gw >= M * Nout) return;
    int m = gw / Nout, j = gw - m * Nout;
    float s = 0.f;
    for (int k = lane; k < K; k += 64)
        s += A[(size_t)m * K + k] * W[(size_t)k * Nout + j];
#pragma unroll
    for (int o = 32; o > 0; o >>= 1) s += __shfl_xor(s, o);
    if (lane == 0) {
        float v = s + b[j];
        if (relu) v = fmaxf(v, 0.f);
        out[(size_t)m * Nout + j] = v;
    }
}

// ---------------- launcher ----------------

extern "C" void kernel_launch(void* const* d_in, const int* in_sizes, int n_in,
                              void* d_out, int out_size, void* d_ws, size_t ws_size,
                              hipStream_t stream) {
    const float* x        = (const float*)d_in[0];
    const float* eattr    = (const float*)d_in[1];
    const int*   eidx     = (const int*)d_in[2];
    const float* deg_hist = (const float*)d_in[4];
    const float* ew0      = (const float*)d_in[5];
    const float* eb0      = (const float*)d_in[6];
    const float* prew0    = (const float*)d_in[7];
    const float* preb0    = (const float*)d_in[8];
    const float* postw0   = (const float*)d_in[9];
    const float* postb0   = (const float*)d_in[10];
    const float* linw0    = (const float*)d_in[11];
    const float* linb0    = (const float*)d_in[12];
    const float* ew       = (const float*)d_in[13];
    const float* eb       = (const float*)d_in[14];
    const float* prew     = (const float*)d_in[15];
    const float* preb     = (const float*)d_in[16];
    const float* postw    = (const float*)d_in[17];
    const float* postb    = (const float*)d_in[18];
    const float* linw     = (const float*)d_in[19];
    const float* linb     = (const float*)d_in[20];
    const float* hw1      = (const float*)d_in[21];
    const float* hb1      = (const float*)d_in[22];
    const float* hw2      = (const float*)d_in[23];
    const float* hb2      = (const float*)d_in[24];
    const float* hw3      = (const float*)d_in[25];
    const float* hb3      = (const float*)d_in[26];

    const int E = N_EDGES;
    const int* srcI = eidx;
    const int* dstI = eidx + E;

    char* w = (char*)d_ws;
    auto carve = [&](size_t bytes) -> void* {
        void* p = (void*)w;
        w += (bytes + 255) & ~(size_t)255;
        return p;
    };
    float* P     = (float*)carve((size_t)3072 * 900 * 4);
    float* Hbuf  = (float*)carve((size_t)3072 * 300 * 4);
    float* hF    = (float*)carve((size_t)3072 * 300 * 4);
    float* W3eff = (float*)carve((size_t)2 * 1800 * 4);
    float* cb    = (float*)carve((size_t)1800 * 4);
    float* degc  = (float*)carve((size_t)3072 * 4);
    float* amp   = (float*)carve((size_t)3072 * 4);
    float* att   = (float*)carve((size_t)3072 * 4);
    float* avgp  = (float*)carve(256);
    float* gpool = (float*)carve((size_t)16 * 300 * 4);
    float* g1    = (float*)carve((size_t)16 * 600 * 4);
    float* g2    = (float*)carve((size_t)16 * 300 * 4);
    float* part  = (float*)carve((size_t)POOL_S * 16 * 300 * 4);
    float2* eag  = (float2*)carve((size_t)E * 8);
    int* deg = (int*)carve((size_t)3072 * 4);
    int* off = (int*)carve((size_t)3073 * 4);
    int* cur = (int*)carve((size_t)3072 * 4);
    int* ce  = (int*)carve((size_t)E * 4);
    int* gs  = (int*)carve((size_t)E * 4);

    u16* u1bf    = (u16*)carve((size_t)3072 * 1800 * 2);
    u16* u2bf    = (u16*)carve((size_t)3072 * 1800 * 2);
    u16* xbf_h   = (u16*)carve((size_t)3072 * 32 * 2);
    u16* xbf_l   = (u16*)carve((size_t)3072 * 32 * 2);
    u16* hbf_h   = (u16*)carve((size_t)3072 * 320 * 2);
    u16* hbf_l   = (u16*)carve((size_t)3072 * 320 * 2);
    u16* pbf_h   = (u16*)carve((size_t)3072 * 320 * 2);
    u16* pbf_l   = (u16*)carve((size_t)3072 * 320 * 2);
    u16* agg_h   = (u16*)carve((size_t)18432 * 1216 * 2);
    u16* Wu0A_h  = (u16*)carve((size_t)704 * 32 * 2);
    u16* Wu0A_l  = (u16*)carve((size_t)704 * 32 * 2);
    u16* WuA_h   = (u16*)carve((size_t)4 * 4096 * 320 * 2);
    u16* WuA_l   = (u16*)carve((size_t)4 * 4096 * 320 * 2);
    u16* Wp0T_h  = (u16*)carve((size_t)6 * 192 * 128 * 2);
    u16* WpT_h   = (u16*)carve((size_t)24 * 192 * 1216 * 2);
    u16* linT_h  = (u16*)carve((size_t)5 * 320 * 320 * 2);
    u16* linT_l  = (u16*)carve((size_t)5 * 320 * 320 * 2);

    // ---- setup ----
    zero_int_k<<<(3072 + 255) / 256, 256, 0, stream>>>(deg, 3072);
    count_deg_k<<<(E + 255) / 256, 256, 0, stream>>>(dstI, deg, E);
    scan_off_k<<<1, 1024, 0, stream>>>(deg, off);
    init_cur_k<<<(3072 + 255) / 256, 256, 0, stream>>>(off, cur, 3072);
    scatter_k<<<(E + 255) / 256, 256, 0, stream>>>(dstI, cur, ce, E);
    gather_idx_k<<<(E + 255) / 256, 256, 0, stream>>>(ce, srcI, eattr, gs, eag, E);
    avg_log_k<<<1, 64, 0, stream>>>(deg_hist, avgp);
    node_scalers_k<<<(3072 + 255) / 256, 256, 0, stream>>>(deg, avgp, degc, amp, att, 3072);

    // ---- conversions ----
    cvt_x_k<<<(3072 * 32 + 255) / 256, 256, 0, stream>>>(x, xbf_h, xbf_l);
    cvt_wu0_k<<<dim3((192 * 32 + 255) / 256, 1, 2), 256, 0, stream>>>(prew0, Wu0A_h, Wu0A_l);
    cvt_wh0_k<<<(320 * 32 + 255) / 256, 256, 0, stream>>>(postw0, Wu0A_h + 384 * 32, Wu0A_l + 384 * 32);
    cvt_wp0_k<<<dim3((192 * 128 + 255) / 256, 1, 6), 256, 0, stream>>>(postw0, Wp0T_h);
    cvt_tr_k<<<dim3(5, 5, 48), 256, 0, stream>>>(prew, WuA_h, WuA_l, 2, 6,
        1620000LL, 90000LL, 270000LL, 0LL, 1310720LL, 593920LL, 96000LL, 300, 300, 300, 320);
    cvt_tr_k<<<dim3(5, 1, 24), 256, 0, stream>>>(postw, WuA_h + 1187840, WuA_l + 1187840, 1, 6,
        1170000LL, 0LL, 195000LL, 0LL, 1310720LL, 0LL, 16000LL, 300, 50, 50, 320);
    cvt_tr_k<<<dim3(19, 1, 72), 256, 0, stream>>>(postw, WpT_h, nullptr, 6, 3,
        1170000LL, 195000LL, 60000LL, 15000LL, 1400832LL, 233472LL, 60800LL, 1200, 50, 50, 1216);
    cvt_tr_k<<<dim3(5, 5, 1), 256, 0, stream>>>(linw0, linT_h, linT_l, 1, 1,
        0LL, 0LL, 0LL, 0LL, 0LL, 0LL, 0LL, 300, 300, 300, 320);
    cvt_tr_k<<<dim3(5, 5, 4), 256, 0, stream>>>(linw, linT_h + 102400, linT_l + 102400, 1, 1,
        90000LL, 0LL, 0LL, 0LL, 102400LL, 0LL, 0LL, 300, 300, 300, 320);

    // ---- layer 0 (Fh=32, TF=192) ----
    {
        zero3_k<<<(3 * 192 + 255) / 256, 256, 0, stream>>>(W3eff, cb, 192);
        prep_edge2_k<<<dim3(1, 3, KC_PREP), 256, 0, stream>>>(
            ew0, eb0, prew0, preb0, W3eff, cb, 32, 192);
        mfma_fu_k<<<dim3(24, 11), 256, 0, stream>>>(
            xbf_h, xbf_l, 32, Wu0A_h, Wu0A_l, 32, 32, cb,
            u1bf, 192, u2bf, 192, Hbuf, 300, 192, 384, 192, 300);
        agg_k<<<((size_t)3072 * 24 + 255) / 256, 256, 0, stream>>>(
            u1bf, u2bf, W3eff, off, gs, eag, degc, agg_h, 32, 192, 192);
        mfma_gemm_t<1, 1, 64><<<dim3(48, 3, 6), 256, 0, stream>>>(
            agg_h, nullptr, 7296, 1216, Wp0T_h, nullptr, 128, 192 * 128, 128, nullptr,
            P, 900, 150, 150, 0, nullptr, nullptr, 0, 0);
        combine_k<<<((size_t)3072 * 300 + 255) / 256, 256, 0, stream>>>(
            Hbuf, P, amp, att, postb0, pbf_h, pbf_l);
        mfma_gemm_t<0, 0, 64><<<dim3(48, 5), 256, 0, stream>>>(
            pbf_h, pbf_l, 320, 0, linT_h, linT_l, 320, 0, 320, linb0,
            hF, 300, 0, 300, 1, hbf_h, hbf_l, 320, 0);
    }

    // ---- layers 1..4 ----
    for (int l = 0; l < N_INNER; l++) {
        zero3_k<<<(3 * 1800 + 255) / 256, 256, 0, stream>>>(W3eff, cb, 1800);
        prep_edge2_k<<<dim3(8, 3, KC_PREP), 256, 0, stream>>>(
            ew + (size_t)l * 600, eb + (size_t)l * 300,
            prew + (size_t)l * 6 * 900 * 300, preb + (size_t)l * 6 * 300, W3eff, cb, 300, 1800);
        mfma_fu_k<<<dim3(24, 63), 256, 0, stream>>>(
            hbf_h, hbf_l, 320,
            WuA_h + (size_t)l * 1310720, WuA_l + (size_t)l * 1310720, 320, 320, cb,
            u1bf, 1800, u2bf, 1800, Hbuf, 300, 1856, 3712, 1800, 300);
        agg_k<<<((size_t)3072 * 225 + 255) / 256, 256, 0, stream>>>(
            u1bf, u2bf, W3eff, off, gs, eag, degc, agg_h, 300, 1800, 1800);
        mfma_gemm_t<1, 1, 64><<<dim3(48, 3, 6), 256, 0, stream>>>(
            agg_h, nullptr, 7296, 1216,
            WpT_h + (size_t)l * 6 * 192 * 1216, nullptr, 1216, 192 * 1216, 1216, nullptr,
            P, 900, 150, 150, 0, nullptr, nullptr, 0, 0);
        combine_k<<<((size_t)3072 * 300 + 255) / 256, 256, 0, stream>>>(
            Hbuf, P, amp, att, postb + (size_t)l * 300, pbf_h, pbf_l);
        int relu = (l < N_INNER - 1) ? 1 : 0;
        mfma_gemm_t<0, 0, 64><<<dim3(48, 5), 256, 0, stream>>>(
            pbf_h, pbf_l, 320, 0,
            linT_h + (size_t)(l + 1) * 102400, linT_l + (size_t)(l + 1) * 102400, 320, 0,
            320, linb + (size_t)l * 300, hF, 300, 0, 300, relu, hbf_h, hbf_l, 320, 0);
    }

    // ---- head ----
    pool_part_k<<<(POOL_S * 16 * 300 + 255) / 256, 256, 0, stream>>>(hF, part);
    pool_red_k<<<(16 * 300 + 255) / 256, 256, 0, stream>>>(part, gpool);
    fc_wave_k<<<((size_t)16 * 600 * 64 + 255) / 256, 256, 0, stream>>>(
        gpool, hw1, hb1, g1, 16, 300, 600, 1);
    fc_wave_k<<<((size_t)16 * 300 * 64 + 255) / 256, 256, 0, stream>>>(
        g1, hw2, hb2, g2, 16, 600, 300, 1);
    fc_wave_k<<<(16 * 64 + 255) / 256, 256, 0, stream>>>(
        g2, hw3, hb3, (float*)d_out, 16, 300, 1, 1);
}